// Round 18
// baseline (7558.784 us; speedup 1.0000x reference)
//
#include <hip/hip_runtime.h>

#define BB 32
#define NN 16384
#define CC 64
#define NC 4096
#define T  512             // 8 waves/block = 2 waves/SIMD on one CU
#define SLOTS (NN / T)     // 32 points per thread

// ---------------------------------------------------------------------------
// FPS, one block per batch. Distance chain B1 = fma(dz,dz, fma(dx,dx, dy*dy))
// — bitwise-verified (R6). R18: dist array moved to LDS.
//   R11-R17 established: ~128-float register state is split ~88 arch VGPR +
//   AGPRs by the allocator at every setting; the dist RMW (accvgpr_write per
//   point per iter) is the unavoidable cost of register homing -> ~2x inst
//   inflation. LDS-homed dist turns the RMW into ds_read+v_min+ds_write on
//   the LDS pipe, which OVERLAPS the VALU pipe (~1024cyc each per iter at
//   2 waves/SIMD -> iter ~= max, not sum). [j][t] layout: lane-contiguous,
//   conflict-free; j is a compile-time constant -> ds ops use immediate
//   offsets off a single base (t*4), zero addressing math.
// Kept (proven): DPP wave-max + single LDS atomicMax on float bits [R14];
// achievers rescan descending + atomicMin = numpy first-occurrence argmax
// [R7+]; compact 12B-row centroid buffer in d_ws (L2-resident) [R12];
// depth-4 sentinel rotation, reset slot (it+2)&3 [R13+]; coords pinned
// non-rematerializable [R17].
// ---------------------------------------------------------------------------

template <int CTRL>
__device__ __forceinline__ float dpp_max(float x) {
    const int yi = __builtin_amdgcn_update_dpp(0, __float_as_int(x),
                                               CTRL, 0xf, 0xf, true);
    return fmaxf(x, __int_as_float(yi));
}

__device__ __forceinline__ float wave_max_dpp(float x) {
    x = dpp_max<0x111>(x);   // row_shr:1
    x = dpp_max<0x112>(x);   // row_shr:2
    x = dpp_max<0x114>(x);   // row_shr:4
    x = dpp_max<0x118>(x);   // row_shr:8
    x = dpp_max<0x142>(x);   // row_bcast:15
    x = dpp_max<0x143>(x);   // row_bcast:31
    return x;                // valid in lane 63
}

// cb0/cstride: centroid re-read source (compact: stride 3; fallback: 64).
__global__ __launch_bounds__(T)
__attribute__((amdgpu_waves_per_eu(2, 2)))
void fps_kernel(const float* __restrict__ in,
                float* __restrict__ out,
                const float* __restrict__ cb0,
                int cstride) {
#pragma clang fp contract(off)
    const int b    = blockIdx.x;
    const int t    = threadIdx.x;
    const int lane = t & 63;

    __shared__ float    s_dist[SLOTS][T];    // 64 KB, lane-contiguous rows
    __shared__ unsigned s_gbits4[4];
    __shared__ int      s_far4[4];

    const float* base = in + (size_t)b * NN * CC;
    const float* cb   = cb0 + (size_t)b * NN * cstride;

    float px[SLOTS], py[SLOTS], pz[SLOTS];
#pragma unroll
    for (int j = 0; j < SLOTS; ++j) {
        const int i = j * T + t;
        const float4 v = *reinterpret_cast<const float4*>(base + (size_t)i * CC);
        px[j] = v.x; py[j] = v.y; pz[j] = v.z;
        s_dist[j][t] = 1e10f;
    }
    // Coords non-rematerializable (no reload-spill to global).
#pragma unroll
    for (int j = 0; j < SLOTS; ++j) {
        asm("" : "+v"(px[j]), "+v"(py[j]), "+v"(pz[j]));
    }
    if (t < 4) { s_far4[t] = 0x7fffffff; s_gbits4[t] = 0u; }

    float cx = base[0], cy = base[1], cz = base[2];   // point 0
    int   far = 0;
    __syncthreads();

    int* idx_out = reinterpret_cast<int*>(out);

    for (int it = 0; it < NC; ++it) {
        if (t == 0) idx_out[((size_t)b * NC + it) * CC] = far;
        if (it == NC - 1) break;

        // ---- dist update (chain B1, bitwise-exact); dist RMW in LDS ----
        float a0 = -1.0f, a1 = -1.0f, a2 = -1.0f, a3 = -1.0f;
#pragma unroll
        for (int j = 0; j < SLOTS; j += 4) {
            {
                const float dx = px[j] - cx, dy = py[j] - cy, dz = pz[j] - cz;
                const float d  = fmaf(dz, dz, fmaf(dx, dx, dy * dy));
                const float nd = fminf(s_dist[j][t], d);
                s_dist[j][t] = nd; a0 = fmaxf(a0, nd);
            }
            {
                const float dx = px[j+1] - cx, dy = py[j+1] - cy, dz = pz[j+1] - cz;
                const float d  = fmaf(dz, dz, fmaf(dx, dx, dy * dy));
                const float nd = fminf(s_dist[j+1][t], d);
                s_dist[j+1][t] = nd; a1 = fmaxf(a1, nd);
            }
            {
                const float dx = px[j+2] - cx, dy = py[j+2] - cy, dz = pz[j+2] - cz;
                const float d  = fmaf(dz, dz, fmaf(dx, dx, dy * dy));
                const float nd = fminf(s_dist[j+2][t], d);
                s_dist[j+2][t] = nd; a2 = fmaxf(a2, nd);
            }
            {
                const float dx = px[j+3] - cx, dy = py[j+3] - cy, dz = pz[j+3] - cz;
                const float d  = fmaf(dz, dz, fmaf(dx, dx, dy * dy));
                const float nd = fminf(s_dist[j+3][t], d);
                s_dist[j+3][t] = nd; a3 = fmaxf(a3, nd);
            }
        }
        const float lv = fmaxf(fmaxf(a0, a1), fmaxf(a2, a3));

        // ---- wave64 max via DPP; lane 63 -> LDS atomicMax on bits ----
        const float wv = wave_max_dpp(lv);
        if (lane == 63)
            atomicMax(&s_gbits4[it & 3], __float_as_uint(wv));

        if (t == 0) {              // reset slot used 2 iters ahead (barrier-safe)
            s_far4[(it + 2) & 3]   = 0x7fffffff;
            s_gbits4[(it + 2) & 3] = 0u;
        }
        __syncthreads();                                  // A

        const float gm = __uint_as_float(s_gbits4[it & 3]);

        // ---- achievers: first local index (descending, from LDS), atomicMin ----
        if (lv == gm) {
            int myi = 0x7fffffff;
#pragma unroll
            for (int j = SLOTS - 1; j >= 0; --j)
                myi = (s_dist[j][t] == gm) ? (j * T + t) : myi;
            atomicMin(&s_far4[it & 3], myi);
        }
        __syncthreads();                                  // B

        far = s_far4[it & 3];

        // ---- centroid reload (compact L2-resident buffer, or strided) ----
        cx = cb[(size_t)far * cstride + 0];
        cy = cb[(size_t)far * cstride + 1];
        cz = cb[(size_t)far * cstride + 2];
    }
}

// ---------------------------------------------------------------------------
// One-time xyz compaction: in[b][i][0..2] -> cpts[b][i*3+{0,1,2}] (12B rows).
// ---------------------------------------------------------------------------
__global__ __launch_bounds__(256) void compact_kernel(const float* __restrict__ in,
                                                      float* __restrict__ cpts) {
    const int gid = blockIdx.x * blockDim.x + threadIdx.x;   // one point each
    const int b   = gid >> 14;                               // NN == 16384
    const int i   = gid & (NN - 1);
    const float* src = in + ((size_t)b * NN + i) * CC;
    float* dst = cpts + ((size_t)b * NN + i) * 3;
    dst[0] = src[0];
    dst[1] = src[1];
    dst[2] = src[2];
}

// ---------------------------------------------------------------------------
// Gather kernel: one wave64 per output row (64 channels).
// ---------------------------------------------------------------------------
__global__ __launch_bounds__(256) void gather_kernel(const float* __restrict__ in,
                                                     float* out) {
    const int gid  = blockIdx.x * blockDim.x + threadIdx.x;
    const int row  = gid >> 6;     // 0 .. B*NC-1
    const int lane = gid & 63;     // channel
    const int b = row >> 12;       // NC == 4096
    const int idx = reinterpret_cast<const int*>(out)[(size_t)row * CC];
    const float v = in[((size_t)b * NN + idx) * CC + lane];
    out[(size_t)row * CC + lane] = v;
}

extern "C" void kernel_launch(void* const* d_in, const int* in_sizes, int n_in,
                              void* d_out, int out_size, void* d_ws, size_t ws_size,
                              hipStream_t stream) {
    const float* in = (const float*)d_in[0];
    float* out = (float*)d_out;

    const size_t ws_need = (size_t)BB * NN * 3 * sizeof(float);   // 6 MB
    if (ws_size >= ws_need) {
        float* cpts = (float*)d_ws;
        compact_kernel<<<(BB * NN) / 256, 256, 0, stream>>>(in, cpts);
        fps_kernel<<<BB, T, 0, stream>>>(in, out, cpts, 3);
    } else {
        fps_kernel<<<BB, T, 0, stream>>>(in, out, in, CC);
    }

    const int total = BB * NC * CC;          // 8,388,608
    gather_kernel<<<total / 256, 256, 0, stream>>>(in, out);
}

// Round 19
// 6884.849 us; speedup vs baseline: 1.0979x; 1.0979x over previous
//
#include <hip/hip_runtime.h>

#define BB 32
#define NN 16384
#define CC 64
#define NC 4096
#define T  512             // 8 waves/block = 2 waves/SIMD on one CU
#define SLOTS (NN / T)     // 32 points per thread

// ---------------------------------------------------------------------------
// FPS, one block per batch. Distance chain B1 = fma(dz,dz, fma(dx,dx, dy*dy))
// — bitwise-verified vs reference (R6, absmax 0).
// R19: the ENTIRE per-iteration update loop is ONE inline-asm block with all
// state as "v"-constrained operands. R11-R18 proved the allocator homes
// ~(state-88) floats in AGPRs at every source/attribute setting, paying
// ~2 accvgpr moves per value per iteration (~2x inst inflation; gfx950 VALU
// cannot read AGPRs). Mandatory asm constraints force arch-VGPR homing:
// satisfying them via AGPR would cost 138 moves/iter, so the allocator's
// cost model must keep the state in VGPRs across the loop.
//   v_subrev_f32 t, s_c, v_p   = p - c  (IEEE sub; SGPR legal in src0)
//   v_mul_f32 / v_fma_f32      = dy*dy, then fma(dx,dx,..), fma(dz,dz,..)
//   v_min_f32 / v_max_f32      = fminf / fmaxf (no NaNs in data)
// 2-point interleave inside the asm hides VALU dep latency.
// Kept (proven): DPP wave-max + LDS atomicMax on float bits [R14]; achievers
// rescan descending + atomicMin = numpy first-occurrence argmax [R7+];
// compact 12B-row centroid buffer in d_ws (L2-resident) [R12]; depth-4
// sentinel rotation, reset slot (it+2)&3 [R13+].
// ---------------------------------------------------------------------------

#define FOR32(M) M(0) M(1) M(2) M(3) M(4) M(5) M(6) M(7) \
                 M(8) M(9) M(10) M(11) M(12) M(13) M(14) M(15) \
                 M(16) M(17) M(18) M(19) M(20) M(21) M(22) M(23) \
                 M(24) M(25) M(26) M(27) M(28) M(29) M(30) M(31)

// One interleaved pair of points (a,b): 16 instructions.
#define PSTR(a, b) \
    "v_subrev_f32 %[t0], %[cx], %[x" #a "]\n\t" \
    "v_subrev_f32 %[t1], %[cy], %[y" #a "]\n\t" \
    "v_subrev_f32 %[t2], %[cz], %[z" #a "]\n\t" \
    "v_subrev_f32 %[t4], %[cx], %[x" #b "]\n\t" \
    "v_subrev_f32 %[t5], %[cy], %[y" #b "]\n\t" \
    "v_subrev_f32 %[t6], %[cz], %[z" #b "]\n\t" \
    "v_mul_f32 %[t3], %[t1], %[t1]\n\t" \
    "v_mul_f32 %[t7], %[t5], %[t5]\n\t" \
    "v_fma_f32 %[t3], %[t0], %[t0], %[t3]\n\t" \
    "v_fma_f32 %[t7], %[t4], %[t4], %[t7]\n\t" \
    "v_fma_f32 %[t3], %[t2], %[t2], %[t3]\n\t" \
    "v_fma_f32 %[t7], %[t6], %[t6], %[t7]\n\t" \
    "v_min_f32 %[d" #a "], %[d" #a "], %[t3]\n\t" \
    "v_min_f32 %[d" #b "], %[d" #b "], %[t7]\n\t" \
    "v_max_f32 %[aa], %[aa], %[d" #a "]\n\t" \
    "v_max_f32 %[ab], %[ab], %[d" #b "]\n\t"

#define DOUT(i) , [d##i] "+v"(dist[i])
#define CIN(i)  , [x##i] "v"(px[i]), [y##i] "v"(py[i]), [z##i] "v"(pz[i])

template <int CTRL>
__device__ __forceinline__ float dpp_max(float x) {
    const int yi = __builtin_amdgcn_update_dpp(0, __float_as_int(x),
                                               CTRL, 0xf, 0xf, true);
    return fmaxf(x, __int_as_float(yi));
}

__device__ __forceinline__ float wave_max_dpp(float x) {
    x = dpp_max<0x111>(x);   // row_shr:1
    x = dpp_max<0x112>(x);   // row_shr:2
    x = dpp_max<0x114>(x);   // row_shr:4
    x = dpp_max<0x118>(x);   // row_shr:8
    x = dpp_max<0x142>(x);   // row_bcast:15
    x = dpp_max<0x143>(x);   // row_bcast:31
    return x;                // valid in lane 63
}

// cb0/cstride: centroid re-read source (compact: stride 3; fallback: 64).
__global__ __launch_bounds__(T)
__attribute__((amdgpu_waves_per_eu(2, 2)))
void fps_kernel(const float* __restrict__ in,
                float* __restrict__ out,
                const float* __restrict__ cb0,
                int cstride) {
#pragma clang fp contract(off)
    const int b    = blockIdx.x;
    const int t    = threadIdx.x;
    const int lane = t & 63;

    __shared__ unsigned s_gbits4[4];
    __shared__ int      s_far4[4];

    const float* base = in + (size_t)b * NN * CC;
    const float* cb   = cb0 + (size_t)b * NN * cstride;

    float px[SLOTS], py[SLOTS], pz[SLOTS], dist[SLOTS];
#pragma unroll
    for (int j = 0; j < SLOTS; ++j) {
        const int i = j * T + t;
        const float4 v = *reinterpret_cast<const float4*>(base + (size_t)i * CC);
        px[j] = v.x; py[j] = v.y; pz[j] = v.z;
        dist[j] = 1e10f;
    }
    if (t < 4) { s_far4[t] = 0x7fffffff; s_gbits4[t] = 0u; }

    float cx = base[0], cy = base[1], cz = base[2];   // point 0
    int   far = 0;
    __syncthreads();

    int* idx_out = reinterpret_cast<int*>(out);

    for (int it = 0; it < NC; ++it) {
        if (t == 0) idx_out[((size_t)b * NC + it) * CC] = far;
        if (it == NC - 1) break;

        // uniform centroid -> SGPRs (legal as VOP2 src0 in the asm)
        const float cxs = __uint_as_float(__builtin_amdgcn_readfirstlane(__float_as_uint(cx)));
        const float cys = __uint_as_float(__builtin_amdgcn_readfirstlane(__float_as_uint(cy)));
        const float czs = __uint_as_float(__builtin_amdgcn_readfirstlane(__float_as_uint(cz)));

        // ---- dist update (chain B1, bitwise-exact): ONE asm block ----
        float accA = -1.0f, accB = -1.0f;
        float q0, q1, q2, q3, q4, q5, q6, q7;
        asm(PSTR(0, 1)   PSTR(2, 3)   PSTR(4, 5)   PSTR(6, 7)
            PSTR(8, 9)   PSTR(10, 11) PSTR(12, 13) PSTR(14, 15)
            PSTR(16, 17) PSTR(18, 19) PSTR(20, 21) PSTR(22, 23)
            PSTR(24, 25) PSTR(26, 27) PSTR(28, 29) PSTR(30, 31)
            : [aa] "+v"(accA), [ab] "+v"(accB),
              [t0] "=&v"(q0), [t1] "=&v"(q1), [t2] "=&v"(q2), [t3] "=&v"(q3),
              [t4] "=&v"(q4), [t5] "=&v"(q5), [t6] "=&v"(q6), [t7] "=&v"(q7)
              FOR32(DOUT)
            : [cx] "s"(cxs), [cy] "s"(cys), [cz] "s"(czs)
              FOR32(CIN));
        const float lv = fmaxf(accA, accB);

        // ---- wave64 max via DPP; lane 63 -> LDS atomicMax on bits ----
        const float wv = wave_max_dpp(lv);
        if (lane == 63)
            atomicMax(&s_gbits4[it & 3], __float_as_uint(wv));

        if (t == 0) {              // reset slot used 2 iters ahead (barrier-safe)
            s_far4[(it + 2) & 3]   = 0x7fffffff;
            s_gbits4[(it + 2) & 3] = 0u;
        }
        __syncthreads();                                  // A

        const float gm = __uint_as_float(s_gbits4[it & 3]);

        // ---- achievers: first local index (descending), atomicMin ----
        if (lv == gm) {
            int myi = 0x7fffffff;
#pragma unroll
            for (int j = SLOTS - 1; j >= 0; --j)
                myi = (dist[j] == gm) ? (j * T + t) : myi;
            atomicMin(&s_far4[it & 3], myi);
        }
        __syncthreads();                                  // B

        far = s_far4[it & 3];

        // ---- centroid reload (compact L2-resident buffer, or strided) ----
        cx = cb[(size_t)far * cstride + 0];
        cy = cb[(size_t)far * cstride + 1];
        cz = cb[(size_t)far * cstride + 2];
    }
}

// ---------------------------------------------------------------------------
// One-time xyz compaction: in[b][i][0..2] -> cpts[b][i*3+{0,1,2}] (12B rows).
// ---------------------------------------------------------------------------
__global__ __launch_bounds__(256) void compact_kernel(const float* __restrict__ in,
                                                      float* __restrict__ cpts) {
    const int gid = blockIdx.x * blockDim.x + threadIdx.x;   // one point each
    const int b   = gid >> 14;                               // NN == 16384
    const int i   = gid & (NN - 1);
    const float* src = in + ((size_t)b * NN + i) * CC;
    float* dst = cpts + ((size_t)b * NN + i) * 3;
    dst[0] = src[0];
    dst[1] = src[1];
    dst[2] = src[2];
}

// ---------------------------------------------------------------------------
// Gather kernel: one wave64 per output row (64 channels).
// ---------------------------------------------------------------------------
__global__ __launch_bounds__(256) void gather_kernel(const float* __restrict__ in,
                                                     float* out) {
    const int gid  = blockIdx.x * blockDim.x + threadIdx.x;
    const int row  = gid >> 6;     // 0 .. B*NC-1
    const int lane = gid & 63;     // channel
    const int b = row >> 12;       // NC == 4096
    const int idx = reinterpret_cast<const int*>(out)[(size_t)row * CC];
    const float v = in[((size_t)b * NN + idx) * CC + lane];
    out[(size_t)row * CC + lane] = v;
}

extern "C" void kernel_launch(void* const* d_in, const int* in_sizes, int n_in,
                              void* d_out, int out_size, void* d_ws, size_t ws_size,
                              hipStream_t stream) {
    const float* in = (const float*)d_in[0];
    float* out = (float*)d_out;

    const size_t ws_need = (size_t)BB * NN * 3 * sizeof(float);   // 6 MB
    if (ws_size >= ws_need) {
        float* cpts = (float*)d_ws;
        compact_kernel<<<(BB * NN) / 256, 256, 0, stream>>>(in, cpts);
        fps_kernel<<<BB, T, 0, stream>>>(in, out, cpts, 3);
    } else {
        fps_kernel<<<BB, T, 0, stream>>>(in, out, in, CC);
    }

    const int total = BB * NC * CC;          // 8,388,608
    gather_kernel<<<total / 256, 256, 0, stream>>>(in, out);
}